// Round 10
// baseline (340.544 us; speedup 1.0000x reference)
//
#include <hip/hip_runtime.h>

typedef unsigned short u16;
typedef unsigned int u32;
typedef short s16x8 __attribute__((ext_vector_type(8)));
typedef short s16x4 __attribute__((ext_vector_type(4)));
typedef float f32x4 __attribute__((ext_vector_type(4)));

__device__ __forceinline__ u16 f2b(float f){
  union { float f; unsigned int i; } v; v.f = f;
  unsigned int r = v.i + 0x7FFFu + ((v.i >> 16) & 1u);
  return (u16)(r >> 16);
}
__device__ __forceinline__ u32 asu(float f){
  union { float f; unsigned int i; } v; v.f = f; return v.i;
}
// pack two f32 -> (bf16(a) | bf16(b)<<16) via v_perm, round-half-up
__device__ __forceinline__ u32 pkbf(float a, float b){
  return __builtin_amdgcn_perm(asu(b) + 0x8000u, asu(a) + 0x8000u, 0x07060302u);
}
// fast GELU (tanh form), __expf -> v_mul+v_exp_f32 (HW transcendental, no libm call)
// 0.5x(1+tanh(0.79788456(x+0.044715x^3))) == x*z/(z+1), z=exp(x*(1.5957692+0.0713548x^2))
__device__ __forceinline__ float gelu_fast(float x){
  float z = __expf(x * (1.5957692f + 0.0713548f * x * x));
  return x * z * __builtin_amdgcn_rcpf(z + 1.f);
}

// async global->LDS, 16B per lane; lds dest wave-uniform base (HW adds lane*16)
__device__ __forceinline__ void gl_lds16(const u16* g, u16* l) {
  __builtin_amdgcn_global_load_lds(
    (const __attribute__((address_space(1))) unsigned int*)(g),
    (__attribute__((address_space(3))) unsigned int*)(l), 16, 0, 0);
}

// ---------------- transpose+convert: in f32 [K][N] -> out bf16 [N][K] ----------------
__global__ __launch_bounds__(256) void transpose_k(const float* __restrict__ in,
                                                   u16* __restrict__ out, int K, int N)
{
  __shared__ u16 tile[32][33];
  const int tx = threadIdx.x, ty = threadIdx.y;
  const int x = blockIdx.x * 32 + tx;
  const int y0 = blockIdx.y * 32;
  #pragma unroll
  for (int j = ty; j < 32; j += 8)
    tile[j][tx] = f2b(in[(size_t)(y0 + j) * N + x]);
  __syncthreads();
  const int x2 = y0 + tx;
  const int y2 = blockIdx.x * 32;
  #pragma unroll
  for (int j = ty; j < 32; j += 8)
    out[(size_t)(y2 + j) * K + x2] = tile[tx][j];
}

// ------- vt_k: V slice of qkv [2048 keys][64 dims] -> vtg[bh][64 dims][2048 keys] -------
__global__ __launch_bounds__(256) void vt_k(const u16* __restrict__ qkv,
                                            u16* __restrict__ vtg)
{
  __shared__ u16 tile[32][33];
  const int bh = blockIdx.z, b = bh >> 4, h = bh & 15;
  const int x0 = blockIdx.x * 32;   // dim tile (0 or 32)
  const int y0 = blockIdx.y * 32;   // key tile
  const int tx = threadIdx.x, ty = threadIdx.y;
  #pragma unroll
  for (int j = ty; j < 32; j += 8)
    tile[j][tx] = qkv[(size_t)(b * 2048 + y0 + j) * 3072 + 2048 + h * 64 + x0 + tx];
  __syncthreads();
  #pragma unroll
  for (int j = ty; j < 32; j += 8)
    vtg[((size_t)bh * 64 + x0 + j) * 2048 + y0 + tx] = tile[tx][j];
}

// ---------------- layernorm: f32 in, bf16 out; one block per row of 1024 ----------------
__global__ __launch_bounds__(256) void ln_k(const float* __restrict__ xin,
                                            const float* __restrict__ g,
                                            const float* __restrict__ be,
                                            u16* __restrict__ out)
{
  const int row = blockIdx.x, tid = threadIdx.x;
  float4 u = *(const float4*)(xin + (size_t)row * 1024 + tid * 4);
  float v[4] = {u.x, u.y, u.z, u.w};
  float sum = v[0] + v[1] + v[2] + v[3];
  float sq  = v[0]*v[0] + v[1]*v[1] + v[2]*v[2] + v[3]*v[3];
  #pragma unroll
  for (int off = 32; off > 0; off >>= 1) {
    sum += __shfl_down(sum, off, 64);
    sq  += __shfl_down(sq,  off, 64);
  }
  __shared__ float ws1[4], ws2[4];
  const int wid = tid >> 6, lane = tid & 63;
  if (lane == 0) { ws1[wid] = sum; ws2[wid] = sq; }
  __syncthreads();
  const float tot  = ws1[0] + ws1[1] + ws1[2] + ws1[3];
  const float tot2 = ws2[0] + ws2[1] + ws2[2] + ws2[3];
  const float inv = 1.0f / 1024.0f;
  const float mu = tot * inv;
  const float var = tot2 * inv - mu * mu;
  const float rs = rsqrtf(var + 1e-5f);
  float4 gv = *(const float4*)(g  + tid * 4);
  float4 bv = *(const float4*)(be + tid * 4);
  u16 ob[4];
  ob[0] = f2b((v[0] - mu) * rs * gv.x + bv.x);
  ob[1] = f2b((v[1] - mu) * rs * gv.y + bv.y);
  ob[2] = f2b((v[2] - mu) * rs * gv.z + bv.z);
  ob[3] = f2b((v[3] - mu) * rs * gv.w + bv.w);
  uint2 o;
  o.x = (unsigned)ob[0] | ((unsigned)ob[1] << 16);
  o.y = (unsigned)ob[2] | ((unsigned)ob[3] << 16);
  *(uint2*)(out + (size_t)row * 1024 + tid * 4) = o;
}

// ---- GEMM A (gl_lds, XOR-swizzled LDS; 0 conflicts measured R7) ----
template<int ACT, bool RES, bool OUTF>
__global__ __launch_bounds__(256) void gemm_lds(const u16* __restrict__ A, int lda,
                                                const u16* __restrict__ Bt, int ldb,
                                                const float* __restrict__ bias,
                                                const float* __restrict__ res,
                                                void* __restrict__ Cout,
                                                int K, int ldc)
{
  __shared__ __align__(16) u16 As[128 * 64];
  __shared__ __align__(16) u16 Bs[128 * 64];
  const int tid = threadIdx.x;
  const int wid = tid >> 6, lane = tid & 63, quad = lane >> 4, ln = lane & 15;
  const int wr = wid >> 1, wc = wid & 1;
  const int m0 = blockIdx.y * 128, n0 = blockIdx.x * 128;

  f32x4 acc[4][4];
  #pragma unroll
  for (int i = 0; i < 4; ++i)
    #pragma unroll
    for (int j = 0; j < 4; ++j)
      #pragma unroll
      for (int r = 0; r < 4; ++r) acc[i][j][r] = 0.f;

  const int srow = wid * 32 + (lane >> 3);
  const int scol = (((lane & 7) ^ (lane >> 3)) & 7) * 8;

  for (int k0 = 0; k0 < K; k0 += 64) {
    __syncthreads();
    #pragma unroll
    for (int i = 0; i < 4; ++i) {
      const int row = srow + i * 8;
      gl_lds16(&A [(size_t)(m0 + row) * lda + k0 + scol], &As[wid * 2048 + i * 512]);
      gl_lds16(&Bt[(size_t)(n0 + row) * ldb + k0 + scol], &Bs[wid * 2048 + i * 512]);
    }
    __syncthreads();
    #pragma unroll
    for (int ks = 0; ks < 2; ++ks) {
      const int cgx = (((4*ks + quad) ^ (ln & 7)) & 7) * 8;
      s16x8 af[4], bfr[4];
      #pragma unroll
      for (int i = 0; i < 4; ++i) af[i]  = *(const s16x8*)&As[(wr*64 + i*16 + ln)*64 + cgx];
      #pragma unroll
      for (int j = 0; j < 4; ++j) bfr[j] = *(const s16x8*)&Bs[(wc*64 + j*16 + ln)*64 + cgx];
      #pragma unroll
      for (int i = 0; i < 4; ++i)
        #pragma unroll
        for (int j = 0; j < 4; ++j)
          acc[i][j] = __builtin_amdgcn_mfma_f32_16x16x32_bf16(af[i], bfr[j], acc[i][j], 0, 0, 0);
    }
  }
  float bv[4];
  #pragma unroll
  for (int j = 0; j < 4; ++j) bv[j] = bias ? bias[n0 + wc*64 + j*16 + ln] : 0.f;
  #pragma unroll
  for (int i = 0; i < 4; ++i) {
    #pragma unroll
    for (int r = 0; r < 4; ++r) {
      const int row = m0 + wr*64 + i*16 + quad*4 + r;
      #pragma unroll
      for (int j = 0; j < 4; ++j) {
        const int col = n0 + wc*64 + j*16 + ln;
        const size_t idx = (size_t)row * ldc + col;
        float v = acc[i][j][r] + bv[j];
        if (RES) v += res[idx];
        if (ACT == 1) v = gelu_fast(v);
        if (OUTF) ((float*)Cout)[idx] = v;
        else      ((u16*)Cout)[idx] = f2b(v);
      }
    }
  }
}

// ---- GEMM B v3 (latency-tolerant, 1-block/CU grids): 512 threads, 128x128 tile,
// LDS double-buffer with XOR swizzle (conflict-free) + 2-deep register prefetch. ----
template<int ACT, bool RES, bool OUTF>
__global__ __launch_bounds__(512) void gemm_pf2(const u16* __restrict__ A, int lda,
                                                const u16* __restrict__ Bt, int ldb,
                                                const float* __restrict__ bias,
                                                const float* __restrict__ res,
                                                void* __restrict__ Cout,
                                                int K, int ldc)
{
  __shared__ __align__(16) u16 As[2][128 * 64];
  __shared__ __align__(16) u16 Bs[2][128 * 64];
  const int tid = threadIdx.x;
  const int wid = tid >> 6, lane = tid & 63, quad = lane >> 4, ln = lane & 15;
  const int wr = wid >> 1, wc = wid & 1;     // wr 0..3 (32-row slab), wc 0..1 (64-col slab)
  const int m0 = blockIdx.x * 128, n0 = blockIdx.y * 128;

  f32x4 acc[2][4];
  #pragma unroll
  for (int i = 0; i < 2; ++i)
    #pragma unroll
    for (int j = 0; j < 4; ++j)
      #pragma unroll
      for (int r = 0; r < 4; ++r) acc[i][j][r] = 0.f;

  const int lr = tid >> 2;            // 0..127
  const int lc = (tid & 3) * 16;      // chunks 2t, 2t+1
  const int s1 = (((tid & 3) * 2)     ^ (lr & 7)) * 8;   // swizzled slots
  const int s2 = (((tid & 3) * 2 + 1) ^ (lr & 7)) * 8;
  const u16* Ab = &A [(size_t)(m0 + lr) * lda + lc];
  const u16* Bb = &Bt[(size_t)(n0 + lr) * ldb + lc];

  s16x8 ra[2], rb[2];
  ra[0] = *(const s16x8*)(Ab);     ra[1] = *(const s16x8*)(Ab + 8);
  rb[0] = *(const s16x8*)(Bb);     rb[1] = *(const s16x8*)(Bb + 8);
  *(s16x8*)&As[0][lr*64 + s1] = ra[0];
  *(s16x8*)&As[0][lr*64 + s2] = ra[1];
  *(s16x8*)&Bs[0][lr*64 + s1] = rb[0];
  *(s16x8*)&Bs[0][lr*64 + s2] = rb[1];
  const int nk = K >> 6;
  if (nk > 1) {
    ra[0] = *(const s16x8*)(Ab + 64);  ra[1] = *(const s16x8*)(Ab + 72);
    rb[0] = *(const s16x8*)(Bb + 64);  rb[1] = *(const s16x8*)(Bb + 72);
  }
  __syncthreads();

  for (int k = 0; k < nk; ++k) {
    if (k + 1 < nk) {
      const int p = (k + 1) & 1;
      *(s16x8*)&As[p][lr*64 + s1] = ra[0];
      *(s16x8*)&As[p][lr*64 + s2] = ra[1];
      *(s16x8*)&Bs[p][lr*64 + s1] = rb[0];
      *(s16x8*)&Bs[p][lr*64 + s2] = rb[1];
      if (k + 2 < nk) {
        const u16* An = Ab + (k + 2) * 64;
        const u16* Bn = Bb + (k + 2) * 64;
        ra[0] = *(const s16x8*)(An);  ra[1] = *(const s16x8*)(An + 8);
        rb[0] = *(const s16x8*)(Bn);  rb[1] = *(const s16x8*)(Bn + 8);
      }
    }
    const int c = k & 1;
    #pragma unroll
    for (int ks = 0; ks < 2; ++ks) {
      const int cgx = (((4*ks + quad) ^ (ln & 7)) & 7) * 8;
      s16x8 af[2], bfr[4];
      #pragma unroll
      for (int i = 0; i < 2; ++i) af[i]  = *(const s16x8*)&As[c][(wr*32 + i*16 + ln)*64 + cgx];
      #pragma unroll
      for (int j = 0; j < 4; ++j) bfr[j] = *(const s16x8*)&Bs[c][(wc*64 + j*16 + ln)*64 + cgx];
      #pragma unroll
      for (int i = 0; i < 2; ++i)
        #pragma unroll
        for (int j = 0; j < 4; ++j)
          acc[i][j] = __builtin_amdgcn_mfma_f32_16x16x32_bf16(af[i], bfr[j], acc[i][j], 0, 0, 0);
    }
    __syncthreads();
  }

  float bv[4];
  #pragma unroll
  for (int j = 0; j < 4; ++j) bv[j] = bias ? bias[n0 + wc*64 + j*16 + ln] : 0.f;
  #pragma unroll
  for (int i = 0; i < 2; ++i) {
    #pragma unroll
    for (int r = 0; r < 4; ++r) {
      const int row = m0 + wr*32 + i*16 + quad*4 + r;
      #pragma unroll
      for (int j = 0; j < 4; ++j) {
        const int col = n0 + wc*64 + j*16 + ln;
        const size_t idx = (size_t)row * ldc + col;
        float v = acc[i][j][r] + bv[j];
        if (RES) v += res[idx];
        if (ACT == 1) v = gelu_fast(v);
        if (OUTF) ((float*)Cout)[idx] = v;
        else      ((u16*)Cout)[idx] = f2b(v);
      }
    }
  }
}

// ---------------- flash attention v5: __expf scores + CU-balanced qb map ----------------
// 1024 blocks in 4 dispatch rounds of 256; CU-group g gets qbs {31-g,16+g,15-g,g}
// summing to 62 for every g -> near-uniform per-CU work.
__global__ __launch_bounds__(256) void attn_k(const u16* __restrict__ qkv,
                                              const u16* __restrict__ vtg,
                                              u16* __restrict__ outp)
{
  __shared__ __align__(16) u16 Kt[64 * 64];   // swizzled [key][dim]
  __shared__ __align__(16) u16 Vt[64 * 64];   // swizzled [dim][key]
  const int tid = threadIdx.x, wid = tid >> 6, lane = tid & 63;
  const int quad = lane >> 4, ln = lane & 15;
  const int c = blockIdx.x & 255, rr = blockIdx.x >> 8;
  const int g = c >> 5, bh = c & 31, b = bh >> 4, h = bh & 15;
  const int qb = (rr == 0) ? (31 - g) : (rr == 1) ? (16 + g) : (rr == 2) ? (15 - g) : g;
  const u16* base = qkv + (size_t)b * 2048 * 3072;
  const u16* vbase = vtg + (size_t)bh * 64 * 2048;
  const float SC = 0.125f;   // 1/sqrt(64)

  const int grow = (lane >> 3);                     // + 16*wid + 8*i
  const int gch  = ((lane & 7) ^ (lane >> 3)) * 8;  // global chunk offset (u16)
  const int qln = qb * 64 + wid * 16 + ln;

  s16x8 aQ0, aQ1;
  {
    const u16* qrow = base + (size_t)qln * 3072 + h * 64 + quad * 8;
    aQ0 = *(const s16x8*)(qrow);
    aQ1 = *(const s16x8*)(qrow + 32);
  }
  f32x4 o[4];
  float lsum = 0.f;
  #pragma unroll
  for (int dt = 0; dt < 4; ++dt)
    #pragma unroll
    for (int r = 0; r < 4; ++r) o[dt][r] = 0.f;

  const int nkt = qb + 1;
  for (int kt = 0; kt < nkt; ++kt) {
    const int kb = kt * 64;
    __syncthreads();
    #pragma unroll
    for (int i = 0; i < 2; ++i) {
      const int r = wid * 16 + i * 8 + grow;
      gl_lds16(base  + (size_t)(kb + r) * 3072 + 1024 + h * 64 + gch, &Kt[wid * 1024 + i * 512]);
      gl_lds16(vbase + (size_t)r * 2048 + kb + gch,                   &Vt[wid * 1024 + i * 512]);
    }
    __syncthreads();

    const int mtn = (kt < qb) ? 4 : (wid + 1);   // diagonal tile: wave-uniform cut
    for (int mt = 0; mt < mtn; ++mt) {
      f32x4 s;
      #pragma unroll
      for (int r = 0; r < 4; ++r) s[r] = 0.f;
      const int krow = (mt*16 + ln) * 64;
      s16x8 k0 = *(const s16x8*)&Kt[krow + ((quad     ^ (ln & 7)) * 8)];
      s16x8 k1 = *(const s16x8*)&Kt[krow + (((4+quad) ^ (ln & 7)) * 8)];
      s = __builtin_amdgcn_mfma_f32_16x16x32_bf16(k0, aQ0, s, 0, 0, 0);
      s = __builtin_amdgcn_mfma_f32_16x16x32_bf16(k1, aQ1, s, 0, 0, 0);
      float p[4];
      #pragma unroll
      for (int r = 0; r < 4; ++r) p[r] = __expf(s[r] * SC);   // v_mul+v_exp_f32
      if (kt == qb && mt == wid) {   // causal mask on the diagonal 16x16, lane-local
        #pragma unroll
        for (int r = 0; r < 4; ++r) if ((quad*4 + r) > ln) p[r] = 0.f;
      }
      lsum += (p[0] + p[1]) + (p[2] + p[3]);
      union { u32 u[2]; s16x4 v; } bp;
      bp.u[0] = pkbf(p[0], p[1]); bp.u[1] = pkbf(p[2], p[3]);
      const int vch = ((2*mt + (quad >> 1)) ^ (ln & 7)) * 8 + (quad & 1) * 4;
      #pragma unroll
      for (int dt = 0; dt < 4; ++dt) {
        s16x4 aV = *(const s16x4*)&Vt[(dt*16 + ln) * 64 + vch];
        o[dt] = __builtin_amdgcn_mfma_f32_16x16x16bf16_1k(aV, bp.v, o[dt], 0, 0, 0);
      }
    }
  }

  lsum += __shfl_xor(lsum, 16, 64);
  lsum += __shfl_xor(lsum, 32, 64);
  const float inv = 1.0f / lsum;

  u16* orow = outp + (size_t)(b * 2048 + qln) * 1024 + h * 64;
  #pragma unroll
  for (int dt = 0; dt < 4; ++dt) {
    uint2 w;
    w.x = pkbf(o[dt][0] * inv, o[dt][1] * inv);
    w.y = pkbf(o[dt][2] * inv, o[dt][3] * inv);
    *(uint2*)(orow + dt*16 + quad*4) = w;
  }
}

// ---------------- launch ----------------
extern "C" void kernel_launch(void* const* d_in, const int* in_sizes, int n_in,
                              void* d_out, int out_size, void* d_ws, size_t ws_size,
                              hipStream_t stream)
{
  (void)in_sizes; (void)n_in; (void)out_size;
  const float* x      = (const float*)d_in[0];
  const float* w_qkv  = (const float*)d_in[1];
  const float* b_qkv  = (const float*)d_in[2];
  const float* w_proj = (const float*)d_in[3];
  const float* b_proj = (const float*)d_in[4];
  const float* g1     = (const float*)d_in[5];
  const float* be1    = (const float*)d_in[6];
  const float* g2     = (const float*)d_in[7];
  const float* be2    = (const float*)d_in[8];
  const float* w_fc1  = (const float*)d_in[9];
  const float* b_fc1  = (const float*)d_in[10];
  const float* w_fc2  = (const float*)d_in[11];
  const float* b_fc2  = (const float*)d_in[12];

  u16* base    = (u16*)d_ws;
  u16* hbuf    = base;                               //  [0, 8) MiB
  u16* wt_qkv  = base + (size_t) 4194304;            //  [8,14)
  u16* wt_proj = base + (size_t) 7340032;            //  [14,16)
  u16* qkvb    = base + (size_t) 8388608;            //  [16,40)  dead after attn
  float* x2f   = (float*)(base + (size_t)8388608);   //  [16,32)  after attn
  u16* wt_fc2  = base + (size_t)16777216;            //  [32,40)  after attn
  u16* wt_fc1  = base + (size_t) 4194304;            //  [8,16)   after proj
  u16* vtg     = base + (size_t)20971520;            //  [40,56)  dead after attn
  u16* fbuf    = base + (size_t)20971520;            //  [40,..)  after attn
  u16* attnb   = (u16*)d_out;
  float* outf  = (float*)d_out;

  dim3 tb(32, 8);

  // stage 1: LN1 + QKV
  ln_k<<<4096, 256, 0, stream>>>(x, g1, be1, hbuf);
  transpose_k<<<dim3(96, 32), tb, 0, stream>>>(w_qkv, wt_qkv, 1024, 3072);
  gemm_lds<0,false,false><<<dim3(24, 32), 256, 0, stream>>>(hbuf, 1024, wt_qkv, 1024,
                                                            b_qkv, nullptr, qkvb, 1024, 3072);
  // stage 2: V pre-transpose + attention (bf16 out into d_out)
  vt_k<<<dim3(2, 64, 32), tb, 0, stream>>>(qkvb, vtg);
  attn_k<<<1024, 256, 0, stream>>>(qkvb, vtg, attnb);

  // stage 3: proj + residual (f32 trunk), then LN2
  transpose_k<<<dim3(32, 128), tb, 0, stream>>>(w_fc2, wt_fc2, 4096, 1024);
  transpose_k<<<dim3(32, 32),  tb, 0, stream>>>(w_proj, wt_proj, 1024, 1024);
  gemm_pf2<0,true,true><<<dim3(32, 8), 512, 0, stream>>>(attnb, 1024, wt_proj, 1024,
                                                         b_proj, x, x2f, 1024, 1024);
  transpose_k<<<dim3(128, 32), tb, 0, stream>>>(w_fc1, wt_fc1, 1024, 4096);
  ln_k<<<4096, 256, 0, stream>>>(x2f, g2, be2, hbuf);

  if (ws_size >= (size_t)72 * 1024 * 1024) {
    // merged MLP: fbuf = [4096][4096] bf16 (32 MiB)
    gemm_lds<1,false,false><<<dim3(32, 32), 256, 0, stream>>>(hbuf, 1024, wt_fc1, 1024,
                                                              b_fc1, nullptr, fbuf, 1024, 4096);
    gemm_pf2<0,true,true><<<dim3(32, 8), 512, 0, stream>>>(fbuf, 4096, wt_fc2, 4096,
                                                           b_fc2, x2f, outf, 4096, 1024);
  } else {
    // chunked MLP (56 MiB path)
    gemm_lds<1,false,false><<<dim3(16, 32), 256, 0, stream>>>(hbuf, 1024, wt_fc1, 1024,
                                                              b_fc1, nullptr, fbuf, 1024, 2048);
    gemm_pf2<0,true,true><<<dim3(32, 8), 512, 0, stream>>>(fbuf, 2048, wt_fc2, 4096,
                                                           b_fc2, x2f, x2f, 2048, 1024);
    gemm_lds<1,false,false><<<dim3(16, 32), 256, 0, stream>>>(hbuf, 1024,
                                                              wt_fc1 + (size_t)2048*1024, 1024,
                                                              b_fc1 + 2048, nullptr, fbuf, 1024, 2048);
    gemm_pf2<0,true,true><<<dim3(32, 8), 512, 0, stream>>>(fbuf, 2048, wt_fc2 + 2048, 4096,
                                                           nullptr, x2f, outf, 2048, 1024);
  }
}